// Round 6
// baseline (4880.630 us; speedup 1.0000x reference)
//
#include <hip/hip_runtime.h>

// ---------------------------------------------------------------------------
// ScaledDotProductAttention with mask + deterministic JAX-threefry dropout.
// B=8 H=16 S=1024 D=64, fp32. Outputs: [output | attn_weights] concatenated.
// Round 7: restore R2's high-ILP phase 1 (16 K float4 batched in VGPRs, then
// 512 FMAs) -- the d-slice loop was VMEM-latency-bound (VALUBusy 68->44%).
// kb is a template parameter: sv[kb][q] fully static, no scratch, no WT
// round-trip. sched_barrier(0) between kb sections bounds register pressure.
// XCD swizzle now h-fastest within XCD for mask L2 reuse (16 heads share
// each mask row-block).
//   - __launch_bounds__(256, 4): 128-reg budget, 4 blocks/CU.
//   - Phase 3: two k-halves through WTh[512][12] (24 KB), hand-unrolled
//     halves (static sv indices), conflict-free b128 reads.
// ---------------------------------------------------------------------------

constexpr int Bc = 8, Hc = 16, Sc = 1024, Dc = 64;
constexpr int TQ  = 8;     // q-rows per block
constexpr int WTP = 12;    // WTh row stride in floats (48B, conflict-free b128)

typedef float v4f __attribute__((ext_vector_type(4)));

#define TF_ROUND(x0, x1, r) { x0 += x1; x1 = ((x1 << (r)) | (x1 >> (32 - (r)))); x1 ^= x0; }

// Exact JAX threefry2x32 (20 rounds, 5 key injections).
__host__ __device__ __forceinline__ void threefry2x32(unsigned k0, unsigned k1,
                                                      unsigned x0, unsigned x1,
                                                      unsigned& o0, unsigned& o1) {
  const unsigned k2 = k0 ^ k1 ^ 0x1BD11BDAu;
  x0 += k0; x1 += k1;
  TF_ROUND(x0, x1, 13) TF_ROUND(x0, x1, 15) TF_ROUND(x0, x1, 26) TF_ROUND(x0, x1, 6)
  x0 += k1; x1 += k2 + 1u;
  TF_ROUND(x0, x1, 17) TF_ROUND(x0, x1, 29) TF_ROUND(x0, x1, 16) TF_ROUND(x0, x1, 24)
  x0 += k2; x1 += k0 + 2u;
  TF_ROUND(x0, x1, 13) TF_ROUND(x0, x1, 15) TF_ROUND(x0, x1, 26) TF_ROUND(x0, x1, 6)
  x0 += k0; x1 += k1 + 3u;
  TF_ROUND(x0, x1, 17) TF_ROUND(x0, x1, 29) TF_ROUND(x0, x1, 16) TF_ROUND(x0, x1, 24)
  x0 += k1; x1 += k2 + 4u;
  TF_ROUND(x0, x1, 13) TF_ROUND(x0, x1, 15) TF_ROUND(x0, x1, 26) TF_ROUND(x0, x1, 6)
  x0 += k2; x1 += k0 + 5u;
  o0 = x0; o1 = x1;
}

// One kb-section of QK^T: batch-load this thread's K row (16 float4 -> 64
// VGPRs, 16 outstanding VMEM), then 8 q-iterations of 64 FMAs with uniform
// Q float4 loads (L1-broadcast). KB is compile-time -> sv[KB][q] static.
template<int KB>
__device__ __forceinline__ void qk_block(const float* __restrict__ Kb,
                                         const float* __restrict__ Qb,
                                         int kl, float (&svk)[8]) {
  const float4* __restrict__ Krow = (const float4*)(Kb + (size_t)(KB * 256 + kl) * Dc);
  float4 kr[16];
  #pragma unroll
  for (int j = 0; j < 16; ++j) kr[j] = Krow[j];
  #pragma unroll
  for (int q = 0; q < 8; ++q) {
    const float4* __restrict__ Qrow = (const float4*)(Qb + (size_t)q * Dc);  // uniform
    float a = 0.f;
    #pragma unroll
    for (int j = 0; j < 16; ++j) {
      const float4 qv = Qrow[j];
      a = fmaf(kr[j].x, qv.x, a);
      a = fmaf(kr[j].y, qv.y, a);
      a = fmaf(kr[j].z, qv.z, a);
      a = fmaf(kr[j].w, qv.w, a);
    }
    svk[q] = a;
  }
}

__global__ __launch_bounds__(256, 4)
void attn_fused(const float* __restrict__ Qg, const float* __restrict__ Kg,
                const float* __restrict__ Vg, const int* __restrict__ Mg,
                float* __restrict__ Og, float* __restrict__ Ag,
                unsigned key0, unsigned key1)
{
  // WTh[k'][q]: half-range transposed weight buffer (k' = k - half*512).
  // 48B rows -> consecutive-k' b128 reads are 2-way (free) bank aliased.
  __shared__ __align__(16) float WTh[512][WTP];   // 24 KB
  __shared__ float REDm[4][8];                    // cross-wave max scratch
  __shared__ float REDs[4][8];                    // cross-wave sum scratch

  // ---- XCD-aware bijective swizzle (nwg=16384, 8 XCDs, round-robin HW map).
  // XCD x owns wg in [x*2048,(x+1)*2048) = exactly batch b=x. Within the XCD,
  // h sweeps FASTEST so all 16 heads reuse the same mask row-block in L2;
  // q-blocks sweep next; K/V for (b,h) stays hot across its 128 q-blocks.
  const unsigned orig = blockIdx.x;
  const unsigned wg   = (orig & 7u) * 2048u + (orig >> 3);
  const int h  = (int)(wg & 15u);
  const int q0 = (int)((wg >> 4) & 127u) * TQ;
  const int b  = (int)(wg >> 11);

  const int tid = threadIdx.x;
  const int w   = tid >> 6;          // wave 0..3
  const int l   = tid & 63;          // lane
  const int kl  = w * 64 + l;        // this thread's k offset within 256-group
  const size_t bh = (size_t)b * Hc + h;

  const float* __restrict__ Kb = Kg + bh * Sc * Dc;
  const float* __restrict__ Vb = Vg + bh * Sc * Dc;
  const float* __restrict__ Qb = Qg + bh * Sc * Dc + (size_t)q0 * Dc;

  // ---- mask bits first (loads issue early; latency hides under threefry) --
  unsigned mbits = 0u;
  {
    const int* __restrict__ mc = Mg + (size_t)b * Sc * Sc + (size_t)q0 * Sc + kl;
    #pragma unroll
    for (int kb = 0; kb < 4; ++kb)
      #pragma unroll
      for (int q = 0; q < 8; ++q)
        mbits |= (mc[(size_t)q * Sc + kb * 256] != 0) ? (1u << (kb * 8 + q)) : 0u;
  }

  // ---- dropout keep bits (pure ALU, index-only) ----
  // bits[i] = o0^o1 of threefry2x32(key, (0, i)); keep if u(bits) < 0.9
  unsigned keep = 0u;
  const unsigned ibase = ((unsigned)((b * Hc + h) * Sc + q0)) * (unsigned)Sc
                         + (unsigned)kl;
  #pragma unroll 8
  for (int t2 = 0; t2 < 32; ++t2) {            // bit t2 = kb*8 + q
    const int kb = t2 >> 3, q = t2 & 7;
    unsigned o0, o1;
    threefry2x32(key0, key1, 0u, ibase + (unsigned)(q * Sc + kb * 256), o0, o1);
    const unsigned bits = o0 ^ o1;
    const float u = __uint_as_float((bits >> 9) | 0x3f800000u) - 1.0f;  // [0,1)
    keep |= (u < 0.9f) ? (1u << t2) : 0u;
  }

  // ---------------- phase 1: scores = (Q.K)/8, straight to registers ------
  // sched_barrier(0) between sections: caps live range of kr[16] to one
  // section (~116 VGPR peak), preventing cross-section load hoisting.
  float sv[4][8];
  qk_block<0>(Kb, Qb, kl, sv[0]);
  __builtin_amdgcn_sched_barrier(0);
  qk_block<1>(Kb, Qb, kl, sv[1]);
  __builtin_amdgcn_sched_barrier(0);
  qk_block<2>(Kb, Qb, kl, sv[2]);
  __builtin_amdgcn_sched_barrier(0);
  qk_block<3>(Kb, Qb, kl, sv[3]);

  // ---------------- phase 2: mask, softmax, dropout ----------------
  const float NEG = -__builtin_inff();
  #pragma unroll
  for (int kb = 0; kb < 4; ++kb)
    #pragma unroll
    for (int q = 0; q < 8; ++q) {
      const float s = sv[kb][q] * 0.125f;      // /sqrt(64), exact pow2
      sv[kb][q] = ((mbits >> (kb * 8 + q)) & 1u) ? s : NEG;
    }

  // row max: in-thread over kb, wave shfl, cross-wave via LDS
  float mx[8];
  #pragma unroll
  for (int q = 0; q < 8; ++q) {
    float m = fmaxf(fmaxf(sv[0][q], sv[1][q]), fmaxf(sv[2][q], sv[3][q]));
    #pragma unroll
    for (int off = 32; off > 0; off >>= 1) m = fmaxf(m, __shfl_xor(m, off));
    if (l == 0) REDm[w][q] = m;
  }
  __syncthreads();
  #pragma unroll
  for (int q = 0; q < 8; ++q)
    mx[q] = fmaxf(fmaxf(REDm[0][q], REDm[1][q]), fmaxf(REDm[2][q], REDm[3][q]));

  // exp + row sum
  #pragma unroll
  for (int kb = 0; kb < 4; ++kb)
    #pragma unroll
    for (int q = 0; q < 8; ++q)
      sv[kb][q] = __expf(sv[kb][q] - mx[q]);   // masked -> exp(-inf)=0
  #pragma unroll
  for (int q = 0; q < 8; ++q) {
    float s = (sv[0][q] + sv[1][q]) + (sv[2][q] + sv[3][q]);
    #pragma unroll
    for (int off = 32; off > 0; off >>= 1) s += __shfl_xor(s, off);
    if (l == 0) REDs[w][q] = s;
  }
  __syncthreads();
  float inv9[8];
  #pragma unroll
  for (int q = 0; q < 8; ++q)
    inv9[q] = 1.0f / (((REDs[0][q] + REDs[1][q]) + (REDs[2][q] + REDs[3][q])) * 0.9f);

  // apply dropout + normalize in place; stream attn_weights to global
  float* __restrict__ Arow = Ag + bh * (size_t)Sc * Sc + (size_t)q0 * Sc + kl;
  #pragma unroll
  for (int kb = 0; kb < 4; ++kb)
    #pragma unroll
    for (int q = 0; q < 8; ++q) {
      const float wv = ((keep >> (kb * 8 + q)) & 1u) ? sv[kb][q] * inv9[q] : 0.f;
      sv[kb][q] = wv;
      __builtin_nontemporal_store(wv, &Arow[(size_t)q * Sc + kb * 256]);
    }

  // ---------------- phase 3: output = W . V, two k-halves ----------------
  // Hand-unrolled halves: every sv index below is compile-time, sv stays in
  // registers. thread: ks = tid&15 (k'-slice), dq = tid>>4 (d-quad).
  // Per k: 2 conflict-free b128 WTh reads feed 32 FMAs; V float4 from L2.
  const int ks = tid & 15;
  const int dq = tid >> 4;           // 0..15
  float4 acc[8];
  #pragma unroll
  for (int q = 0; q < 8; ++q) acc[q] = make_float4(0.f, 0.f, 0.f, 0.f);

#define ACCQ(qi, wq) { acc[qi].x = fmaf(wq, vv.x, acc[qi].x); \
                       acc[qi].y = fmaf(wq, vv.y, acc[qi].y); \
                       acc[qi].z = fmaf(wq, vv.z, acc[qi].z); \
                       acc[qi].w = fmaf(wq, vv.w, acc[qi].w); }
#define PV_COMPUTE(halfc)                                                    \
    _Pragma("unroll 4")                                                      \
    for (int i = 0; i < 32; ++i) {                                           \
      const int kr = i * 16 + ks;                                            \
      const float4 vv = *(const float4*)(Vb + (size_t)((halfc) * 512 + kr) * Dc + dq * 4); \
      const float4 lo = *(const float4*)&WTh[kr][0];                         \
      const float4 hi = *(const float4*)&WTh[kr][4];                         \
      ACCQ(0, lo.x) ACCQ(1, lo.y) ACCQ(2, lo.z) ACCQ(3, lo.w)                \
      ACCQ(4, hi.x) ACCQ(5, hi.y) ACCQ(6, hi.z) ACCQ(7, hi.w)                \
    }

  // ---- half 0: kb = 0,1 ----
  *(float4*)&WTh[kl][0]       = make_float4(sv[0][0], sv[0][1], sv[0][2], sv[0][3]);
  *(float4*)&WTh[kl][4]       = make_float4(sv[0][4], sv[0][5], sv[0][6], sv[0][7]);
  *(float4*)&WTh[256 + kl][0] = make_float4(sv[1][0], sv[1][1], sv[1][2], sv[1][3]);
  *(float4*)&WTh[256 + kl][4] = make_float4(sv[1][4], sv[1][5], sv[1][6], sv[1][7]);
  __syncthreads();                 // half-buffer complete
  PV_COMPUTE(0)

  __syncthreads();                 // all reads of half 0 done
  // ---- half 1: kb = 2,3 ----
  *(float4*)&WTh[kl][0]       = make_float4(sv[2][0], sv[2][1], sv[2][2], sv[2][3]);
  *(float4*)&WTh[kl][4]       = make_float4(sv[2][4], sv[2][5], sv[2][6], sv[2][7]);
  *(float4*)&WTh[256 + kl][0] = make_float4(sv[3][0], sv[3][1], sv[3][2], sv[3][3]);
  *(float4*)&WTh[256 + kl][4] = make_float4(sv[3][4], sv[3][5], sv[3][6], sv[3][7]);
  __syncthreads();                 // half-buffer complete
  PV_COMPUTE(1)

#undef PV_COMPUTE
#undef ACCQ

  // reduce over the 16 k-slices (lane bits 0..3); dq groups unaffected
  #pragma unroll
  for (int off = 1; off <= 8; off <<= 1) {
    #pragma unroll
    for (int q = 0; q < 8; ++q) {
      acc[q].x += __shfl_xor(acc[q].x, off);
      acc[q].y += __shfl_xor(acc[q].y, off);
      acc[q].z += __shfl_xor(acc[q].z, off);
      acc[q].w += __shfl_xor(acc[q].w, off);
    }
  }
  if ((l & 15) == 0) {
    float* __restrict__ Obase = Og + bh * (size_t)Sc * Dc + (size_t)q0 * Dc + dq * 4;
    #pragma unroll
    for (int q = 0; q < 8; ++q) {
      const v4f t = { acc[q].x, acc[q].y, acc[q].z, acc[q].w };
      __builtin_nontemporal_store(t, (v4f*)(Obase + (size_t)q * Dc));
    }
  }
}

extern "C" void kernel_launch(void* const* d_in, const int* in_sizes, int n_in,
                              void* d_out, int out_size, void* d_ws, size_t ws_size,
                              hipStream_t stream) {
  const float* Qg = (const float*)d_in[0];
  const float* Kg = (const float*)d_in[1];
  const float* Vg = (const float*)d_in[2];
  const int*   Mg = (const int*)d_in[3];
  float* Og = (float*)d_out;
  float* Ag = Og + (size_t)Bc * Hc * Sc * Dc;   // attn_weights after output

  // drop_key = fold_in(key(42), 7) = threefry2x32(key=[0,42], counts=[0,7])
  unsigned k0, k1;
  threefry2x32(0u, 42u, 0u, 7u, k0, k1);

  attn_fused<<<dim3(16384), 256, 0, stream>>>(Qg, Kg, Vg, Mg, Og, Ag, k0, k1);
}

// Round 7
// 1719.940 us; speedup vs baseline: 2.8377x; 2.8377x over previous
//
#include <hip/hip_runtime.h>

// ---------------------------------------------------------------------------
// ScaledDotProductAttention with mask + deterministic JAX-threefry dropout.
// B=8 H=16 S=1024 D=64, fp32. Outputs: [output | attn_weights] concatenated.
// Round 8: merge of the two best verified structures.
//   - Phase 1 = R2's (1445us, 68% busy, no spill): per kb-section batch-load
//     kr[16] (high ILP), 512 FMAs over 8 uniform Q rows, park scores in the
//     thread's OWN WT rows (keeps register pressure low; compiler re-rolls).
//   - WT is full [1024][12] (48 KB) so NO sv carry into phase 3 (the R3-R6
//     spill trap). Phase 2 reads scores back, softmaxes in registers, writes
//     final weights back in place.
//   - Phase 3 = R5's: per k, 2 conflict-free b128 WT reads + direct-global V
//     feed 32 FMAs; in-wave shfl reduce; NT stores. 3 barriers total
//     (R2's phase 3 had 64).
//   - q0-fastest XCD swizzle (concurrent blocks of an XCD share one (b,h)
//     K/V working set ~0.5MB in its private L2).
// ---------------------------------------------------------------------------

constexpr int Bc = 8, Hc = 16, Sc = 1024, Dc = 64;
constexpr int TQ  = 8;     // q-rows per block
constexpr int WTP = 12;    // WT row stride in floats (48B: b128 reads 2-way max)

typedef float v4f __attribute__((ext_vector_type(4)));

#define TF_ROUND(x0, x1, r) { x0 += x1; x1 = ((x1 << (r)) | (x1 >> (32 - (r)))); x1 ^= x0; }

// Exact JAX threefry2x32 (20 rounds, 5 key injections).
__host__ __device__ __forceinline__ void threefry2x32(unsigned k0, unsigned k1,
                                                      unsigned x0, unsigned x1,
                                                      unsigned& o0, unsigned& o1) {
  const unsigned k2 = k0 ^ k1 ^ 0x1BD11BDAu;
  x0 += k0; x1 += k1;
  TF_ROUND(x0, x1, 13) TF_ROUND(x0, x1, 15) TF_ROUND(x0, x1, 26) TF_ROUND(x0, x1, 6)
  x0 += k1; x1 += k2 + 1u;
  TF_ROUND(x0, x1, 17) TF_ROUND(x0, x1, 29) TF_ROUND(x0, x1, 16) TF_ROUND(x0, x1, 24)
  x0 += k2; x1 += k0 + 2u;
  TF_ROUND(x0, x1, 13) TF_ROUND(x0, x1, 15) TF_ROUND(x0, x1, 26) TF_ROUND(x0, x1, 6)
  x0 += k0; x1 += k1 + 3u;
  TF_ROUND(x0, x1, 17) TF_ROUND(x0, x1, 29) TF_ROUND(x0, x1, 16) TF_ROUND(x0, x1, 24)
  x0 += k1; x1 += k2 + 4u;
  TF_ROUND(x0, x1, 13) TF_ROUND(x0, x1, 15) TF_ROUND(x0, x1, 26) TF_ROUND(x0, x1, 6)
  x0 += k2; x1 += k0 + 5u;
  o0 = x0; o1 = x1;
}

__global__ __launch_bounds__(256, 3)
void attn_fused(const float* __restrict__ Qg, const float* __restrict__ Kg,
                const float* __restrict__ Vg, const int* __restrict__ Mg,
                float* __restrict__ Og, float* __restrict__ Ag,
                unsigned key0, unsigned key1)
{
  // WT[k][q]: transposed score/weight buffer, full k-range. 48B rows ->
  // b128 reads by consecutive-k lanes are at most 2-way (free) bank aliased.
  __shared__ __align__(16) float WT[Sc][WTP];   // 48 KB
  __shared__ float REDm[4][8];                  // cross-wave max scratch
  __shared__ float REDs[4][8];                  // cross-wave sum scratch

  // ---- XCD-aware bijective swizzle (nwg=16384, 8 XCDs, round-robin HW map).
  // XCD x owns wg in [x*2048,(x+1)*2048) = batch b=x; q0 sweeps fastest
  // within (b,h) so the ~128 concurrent blocks per XCD share one (b,h)'s
  // K/V (512 KB) in the XCD-private L2.
  const unsigned orig = blockIdx.x;
  const unsigned wg   = (orig & 7u) * 2048u + (orig >> 3);
  const int q0 = (int)(wg & 127u) * TQ;
  const int h  = (int)(wg >> 7) & 15;
  const int b  = (int)(wg >> 11);

  const int tid = threadIdx.x;
  const int w   = tid >> 6;          // wave 0..3
  const int l   = tid & 63;          // lane
  const size_t bh = (size_t)b * Hc + h;

  const float* __restrict__ Kb = Kg + bh * Sc * Dc;
  const float* __restrict__ Vb = Vg + bh * Sc * Dc;
  const float* __restrict__ Qb = Qg + bh * Sc * Dc + (size_t)q0 * Dc;

  // ---- mask bits first (loads issue early; latency hides under threefry) --
  unsigned mbits = 0u;
  {
    const int* __restrict__ mc = Mg + (size_t)b * Sc * Sc + (size_t)q0 * Sc + tid;
    #pragma unroll
    for (int kb = 0; kb < 4; ++kb)
      #pragma unroll
      for (int q = 0; q < 8; ++q)
        mbits |= (mc[(size_t)q * Sc + kb * 256] != 0) ? (1u << (kb * 8 + q)) : 0u;
  }

  // ---- dropout keep bits (pure ALU, index-only) ----
  // bits[i] = o0^o1 of threefry2x32(key, (0, i)); keep if u(bits) < 0.9
  unsigned keep = 0u;
  const unsigned ibase = ((unsigned)((b * Hc + h) * Sc + q0)) * (unsigned)Sc
                         + (unsigned)tid;
  #pragma unroll 8
  for (int t2 = 0; t2 < 32; ++t2) {            // bit t2 = kb*8 + q
    const int kb = t2 >> 3, q = t2 & 7;
    unsigned o0, o1;
    threefry2x32(key0, key1, 0u, ibase + (unsigned)(q * Sc + kb * 256), o0, o1);
    const unsigned bits = o0 ^ o1;
    const float u = __uint_as_float((bits >> 9) | 0x3f800000u) - 1.0f;  // [0,1)
    keep |= (u < 0.9f) ? (1u << t2) : 0u;
  }

  // ---------------- phase 1: scores = (Q.K)/8 -> WT (own rows) -------------
  // R2 structure: batch this thread's K row (16 float4, 16 outstanding VMEM),
  // then 8 q-iterations of 64 FMAs with uniform Q loads. Scores parked in
  // WT so NOTHING is carried in registers into later phases.
  #pragma unroll 1
  for (int kb = 0; kb < 4; ++kb) {
    const int k = kb * 256 + tid;
    const float4* __restrict__ Krow = (const float4*)(Kb + (size_t)k * Dc);
    float4 kr[16];
    #pragma unroll
    for (int j = 0; j < 16; ++j) kr[j] = Krow[j];
    float acc[8];
    #pragma unroll
    for (int q = 0; q < 8; ++q) {
      const float4* __restrict__ Qrow = (const float4*)(Qb + (size_t)q * Dc);  // uniform
      float a = 0.f;
      #pragma unroll
      for (int j = 0; j < 16; ++j) {
        const float4 qv = Qrow[j];
        a = fmaf(kr[j].x, qv.x, a);
        a = fmaf(kr[j].y, qv.y, a);
        a = fmaf(kr[j].z, qv.z, a);
        a = fmaf(kr[j].w, qv.w, a);
      }
      acc[q] = a * 0.125f;           // /sqrt(64), exact pow2
    }
    // park in own rows (same-thread readback; no sync needed)
    *(float4*)&WT[k][0] = make_float4(acc[0], acc[1], acc[2], acc[3]);
    *(float4*)&WT[k][4] = make_float4(acc[4], acc[5], acc[6], acc[7]);
  }

  // ---------------- phase 2: mask, softmax, dropout ----------------
  const float NEG = -__builtin_inff();
  float sv[4][8];                    // fully static-indexed from here on
  #pragma unroll
  for (int kb = 0; kb < 4; ++kb) {
    const int k = kb * 256 + tid;
    const float4 lo = *(const float4*)&WT[k][0];
    const float4 hi = *(const float4*)&WT[k][4];
    sv[kb][0] = lo.x; sv[kb][1] = lo.y; sv[kb][2] = lo.z; sv[kb][3] = lo.w;
    sv[kb][4] = hi.x; sv[kb][5] = hi.y; sv[kb][6] = hi.z; sv[kb][7] = hi.w;
    #pragma unroll
    for (int q = 0; q < 8; ++q)
      if (!((mbits >> (kb * 8 + q)) & 1u)) sv[kb][q] = NEG;
  }

  // row max: in-thread over kb, wave shfl, cross-wave via LDS
  float mx[8];
  #pragma unroll
  for (int q = 0; q < 8; ++q) {
    float m = fmaxf(fmaxf(sv[0][q], sv[1][q]), fmaxf(sv[2][q], sv[3][q]));
    #pragma unroll
    for (int off = 32; off > 0; off >>= 1) m = fmaxf(m, __shfl_xor(m, off));
    if (l == 0) REDm[w][q] = m;
  }
  __syncthreads();
  #pragma unroll
  for (int q = 0; q < 8; ++q)
    mx[q] = fmaxf(fmaxf(REDm[0][q], REDm[1][q]), fmaxf(REDm[2][q], REDm[3][q]));

  // exp + row sum
  #pragma unroll
  for (int kb = 0; kb < 4; ++kb)
    #pragma unroll
    for (int q = 0; q < 8; ++q)
      sv[kb][q] = __expf(sv[kb][q] - mx[q]);   // masked -> exp(-inf)=0
  #pragma unroll
  for (int q = 0; q < 8; ++q) {
    float s = (sv[0][q] + sv[1][q]) + (sv[2][q] + sv[3][q]);
    #pragma unroll
    for (int off = 32; off > 0; off >>= 1) s += __shfl_xor(s, off);
    if (l == 0) REDs[w][q] = s;
  }
  __syncthreads();
  float inv9[8];
  #pragma unroll
  for (int q = 0; q < 8; ++q)
    inv9[q] = 1.0f / (((REDs[0][q] + REDs[1][q]) + (REDs[2][q] + REDs[3][q])) * 0.9f);

  // apply dropout + normalize; stream attn_weights; final weights into WT
  float* __restrict__ Arow = Ag + bh * (size_t)Sc * Sc + (size_t)q0 * Sc + tid;
  #pragma unroll
  for (int kb = 0; kb < 4; ++kb) {
    const int k = kb * 256 + tid;
    float wv[8];
    #pragma unroll
    for (int q = 0; q < 8; ++q) {
      wv[q] = ((keep >> (kb * 8 + q)) & 1u) ? sv[kb][q] * inv9[q] : 0.f;
      __builtin_nontemporal_store(wv[q], &Arow[(size_t)q * Sc + kb * 256]);
    }
    *(float4*)&WT[k][0] = make_float4(wv[0], wv[1], wv[2], wv[3]);
    *(float4*)&WT[k][4] = make_float4(wv[4], wv[5], wv[6], wv[7]);
  }
  __syncthreads();                   // WT complete for cross-thread reads

  // ---------------- phase 3: output = W . V ----------------
  // thread: ks = tid&15 (k-slice, k = i*16+ks), dq = tid>>4 (d-quad).
  // Per k: 2 conflict-free b128 WT reads feed 32 FMAs; V float4 from L2.
  const int ks = tid & 15;
  const int dq = tid >> 4;           // 0..15
  float4 acc[8];
  #pragma unroll
  for (int q = 0; q < 8; ++q) acc[q] = make_float4(0.f, 0.f, 0.f, 0.f);

  #pragma unroll 4
  for (int i = 0; i < 64; ++i) {
    const int k = i * 16 + ks;
    const float4 vv = *(const float4*)(Vb + (size_t)k * Dc + dq * 4);
    const float4 lo = *(const float4*)&WT[k][0];
    const float4 hi = *(const float4*)&WT[k][4];
#define ACCQ(qi, wq) { acc[qi].x = fmaf(wq, vv.x, acc[qi].x); \
                       acc[qi].y = fmaf(wq, vv.y, acc[qi].y); \
                       acc[qi].z = fmaf(wq, vv.z, acc[qi].z); \
                       acc[qi].w = fmaf(wq, vv.w, acc[qi].w); }
    ACCQ(0, lo.x) ACCQ(1, lo.y) ACCQ(2, lo.z) ACCQ(3, lo.w)
    ACCQ(4, hi.x) ACCQ(5, hi.y) ACCQ(6, hi.z) ACCQ(7, hi.w)
#undef ACCQ
  }

  // reduce over the 16 k-slices (lane bits 0..3); dq groups unaffected
  #pragma unroll
  for (int off = 1; off <= 8; off <<= 1) {
    #pragma unroll
    for (int q = 0; q < 8; ++q) {
      acc[q].x += __shfl_xor(acc[q].x, off);
      acc[q].y += __shfl_xor(acc[q].y, off);
      acc[q].z += __shfl_xor(acc[q].z, off);
      acc[q].w += __shfl_xor(acc[q].w, off);
    }
  }
  if ((l & 15) == 0) {
    float* __restrict__ Obase = Og + bh * (size_t)Sc * Dc + (size_t)q0 * Dc + dq * 4;
    #pragma unroll
    for (int q = 0; q < 8; ++q) {
      const v4f t = { acc[q].x, acc[q].y, acc[q].z, acc[q].w };
      __builtin_nontemporal_store(t, (v4f*)(Obase + (size_t)q * Dc));
    }
  }
}

extern "C" void kernel_launch(void* const* d_in, const int* in_sizes, int n_in,
                              void* d_out, int out_size, void* d_ws, size_t ws_size,
                              hipStream_t stream) {
  const float* Qg = (const float*)d_in[0];
  const float* Kg = (const float*)d_in[1];
  const float* Vg = (const float*)d_in[2];
  const int*   Mg = (const int*)d_in[3];
  float* Og = (float*)d_out;
  float* Ag = Og + (size_t)Bc * Hc * Sc * Dc;   // attn_weights after output

  // drop_key = fold_in(key(42), 7) = threefry2x32(key=[0,42], counts=[0,7])
  unsigned k0, k1;
  threefry2x32(0u, 42u, 0u, 7u, k0, k1);

  attn_fused<<<dim3(16384), 256, 0, stream>>>(Qg, Kg, Vg, Mg, Og, Ag, k0, k1);
}